// Round 2
// baseline (11653.999 us; speedup 1.0000x reference)
//
#include <hip/hip_runtime.h>
#include <math.h>

// B=16, T=8, C=3, H=W=14, HID=32, IND=16, N=3
// hidden[n]: (16,32,14,14) = 100352 floats

// -------------------------------------------------------------------------
// Head matmul (small N): out[b,n] = dot(in[b,:K], W[n,:K]) + bias[n]
// (kept from round 1; used only for fc1/fc2)
// -------------------------------------------------------------------------
template<bool RELU_IN, bool RELU_OUT>
__global__ __launch_bounds__(256) void matmul_tn(
    const float* __restrict__ in, int in_stride,
    const float* __restrict__ W, const float* __restrict__ bias,
    float* __restrict__ out, int N, int K)
{
    __shared__ float lds[16 * 512];
    const int tid  = threadIdx.x;
    const int wave = tid >> 6;
    const int lane = tid & 63;
    const int n0   = blockIdx.x * 16 + wave * 4;

    bool rv[4];
    const float* wr[4];
#pragma unroll
    for (int r = 0; r < 4; ++r) {
        rv[r] = (n0 + r) < N;
        wr[r] = W + (size_t)(n0 + r) * K;
    }

    float acc[4][16];
#pragma unroll
    for (int r = 0; r < 4; ++r)
#pragma unroll
        for (int b = 0; b < 16; ++b) acc[r][b] = 0.f;

    for (int k0 = 0; k0 < K; k0 += 512) {
        const int len = min(512, K - k0);
        __syncthreads();
        for (int i = tid; i < 16 * 512; i += 256) {
            const int b = i >> 9, kk = i & 511;
            if (kk < len) {
                float v = in[b * in_stride + k0 + kk];
                if (RELU_IN) v = fmaxf(v, 0.f);
                lds[i] = v;
            }
        }
        __syncthreads();
        for (int kk = lane * 4; kk < len; kk += 256) {
            float4 w[4];
#pragma unroll
            for (int r = 0; r < 4; ++r)
                w[r] = rv[r] ? *(const float4*)(wr[r] + k0 + kk)
                             : make_float4(0.f, 0.f, 0.f, 0.f);
#pragma unroll
            for (int b = 0; b < 16; ++b) {
                const float4 v = *(const float4*)(&lds[(b << 9) + kk]);
#pragma unroll
                for (int r = 0; r < 4; ++r) {
                    acc[r][b] += w[r].x * v.x + w[r].y * v.y +
                                 w[r].z * v.z + w[r].w * v.w;
                }
            }
        }
    }

#pragma unroll
    for (int r = 0; r < 4; ++r) {
        const float brv = rv[r] ? bias[n0 + r] : 0.f;
#pragma unroll
        for (int b = 0; b < 16; ++b) {
            float v = acc[r][b];
#pragma unroll
            for (int off = 32; off > 0; off >>= 1)
                v += __shfl_down(v, off, 64);
            if (lane == 0 && rv[r]) {
                v += brv;
                if (RELU_OUT) v = fmaxf(v, 0.f);
                out[b * N + (n0 + r)] = v;
            }
        }
    }
}

// -------------------------------------------------------------------------
// Split-K streaming matmul. out-partial[(n*16+b)*S + s].
// lane: b = lane>>2 (batch), kq = lane&3 (k-quad). Wave: 8 rows; block: 32.
// MODE 0: input = in[b*in_stride + col] (raw)
// MODE 1: input = maxpool3x3(h) with h (16,32,14,14), col = c*196 + y*14 + x
// N must be a multiple of 32. Tails of K-chunks must be multiples of 4 (true
// for all uses here).
// -------------------------------------------------------------------------
template<int MODE>
__global__ __launch_bounds__(256) void matmul_split(
    const float* __restrict__ in, int in_stride,
    const float* __restrict__ W,
    float* __restrict__ partial, int N, int K, int KSLICE, int S)
{
    __shared__ float lds[16 * 516];   // pad 512->516 for even bank spread
    const int tid  = threadIdx.x;
    const int wave = tid >> 6;
    const int lane = tid & 63;
    const int b    = lane >> 2;
    const int kq4  = (lane & 3) * 4;
    const int n0w  = blockIdx.x * 32 + wave * 8;
    const int s    = blockIdx.y;
    const int kb   = s * KSLICE;
    const int ke   = min(K, kb + KSLICE);

    const float* wrow = W + (size_t)n0w * K;

    float acc[8];
#pragma unroll
    for (int r = 0; r < 8; ++r) acc[r] = 0.f;

    for (int k0 = kb; k0 < ke; k0 += 512) {
        const int len = (ke - k0 < 512) ? (ke - k0) : 512;
        __syncthreads();
        for (int i = tid; i < 16 * 512; i += 256) {
            const int kk = i & 511;
            if (kk < len) {
                const int bb  = i >> 9;
                const int col = k0 + kk;
                float v;
                if (MODE == 0) {
                    v = in[bb * in_stride + col];
                } else {
                    const int c = col / 196, p = col - c * 196;
                    const int y = p / 14, x = p - y * 14;
                    const float* hb = in + (bb * 32 + c) * 196;
                    const int y0 = y > 0 ? y - 1 : 0, y1 = y < 13 ? y + 1 : 13;
                    const int x0 = x > 0 ? x - 1 : 0, x1 = x < 13 ? x + 1 : 13;
                    float m = -INFINITY;
                    for (int yy = y0; yy <= y1; ++yy)
                        for (int xx = x0; xx <= x1; ++xx)
                            m = fmaxf(m, hb[yy * 14 + xx]);
                    v = m;
                }
                lds[bb * 516 + kk] = v;
            }
        }
        __syncthreads();
#pragma unroll 2
        for (int kk = 0; kk < len; kk += 16) {
            const int kc = kk + kq4;
            if (kc < len) {
                const float4 vA = *(const float4*)(&lds[b * 516 + kc]);
                const float* wp = wrow + k0 + kc;
#pragma unroll
                for (int r = 0; r < 8; ++r) {
                    const float4 w = *(const float4*)(wp + (size_t)r * K);
                    float a = acc[r];
                    a = fmaf(w.x, vA.x, a);
                    a = fmaf(w.y, vA.y, a);
                    a = fmaf(w.z, vA.z, a);
                    a = fmaf(w.w, vA.w, a);
                    acc[r] = a;
                }
            }
        }
    }

#pragma unroll
    for (int r = 0; r < 8; ++r) {
        float v = acc[r];
        v += __shfl_down(v, 1);
        v += __shfl_down(v, 2);
        if ((lane & 3) == 0)
            partial[((size_t)(n0w + r) * 16 + b) * S + s] = v;
    }
}

// -------------------------------------------------------------------------
// partial[(n*16+b)*S + s] -> out[b*N + n] = bias[n] + sum_s partial
// -------------------------------------------------------------------------
__global__ __launch_bounds__(256) void reduce_partial(
    const float* __restrict__ partial, const float* __restrict__ bias,
    float* __restrict__ out, int N, int S)
{
    const int i = blockIdx.x * 256 + threadIdx.x;
    if (i >= N * 16) return;
    const int n = i >> 4, bb = i & 15;
    const float* p = partial + (size_t)i * S;
    float v = bias[n];
    for (int s = 0; s < S; ++s) v += p[s];
    out[bb * N + n] = v;
}

// -------------------------------------------------------------------------
// Gate conv: sigmoid(conv3x3(cat[bu(16ch), h(32ch)] (+ td), Wg, bg))
// o in [0,32): rh = g*h ; o in [32,64): z = g
// -------------------------------------------------------------------------
template<bool HAS_TD>
__global__ __launch_bounds__(256) void gate_conv(
    const float* __restrict__ bu, const float* __restrict__ h,
    const float* __restrict__ td,
    const float* __restrict__ Wg, const float* __restrict__ bg,
    float* __restrict__ rh, float* __restrict__ z)
{
    int i = blockIdx.x * 256 + threadIdx.x;
    if (i >= 16 * 64 * 196) return;
    int p = i % 196;
    int rest = i / 196;
    int o = rest & 63;
    int b = rest >> 6;
    int y = p / 14, x = p - y * 14;
    int ky0 = (y == 0) ? 1 : 0, ky1 = (y == 13) ? 2 : 3;
    int kx0 = (x == 0) ? 1 : 0, kx1 = (x == 13) ? 2 : 3;

    float acc = bg[o];
    const float* wb  = Wg + o * 432;
    const float* bub = bu + b * 3136;
    const float* hb  = h  + b * 6272;
    const float* tdb = HAS_TD ? td + b * 9408 : nullptr;

    for (int ci = 0; ci < 48; ++ci) {
        const float* src = (ci < 16) ? (bub + ci * 196) : (hb + (ci - 16) * 196);
        const float* w   = wb + ci * 9;
        const float* tp  = HAS_TD ? (tdb + ci * 196) : nullptr;
        for (int ky = ky0; ky < ky1; ++ky) {
            int q = p + (ky - 1) * 14 - 1;
            for (int kx = kx0; kx < kx1; ++kx) {
                float v = src[q + kx];
                if (HAS_TD) v += tp[q + kx];
                acc += v * w[ky * 3 + kx];
            }
        }
    }
    float g = 1.f / (1.f + expf(-acc));
    if (o < 32) {
        int idx = (b * 32 + o) * 196 + p;
        rh[idx] = g * h[idx];
    } else {
        int idx = (b * 32 + (o - 32)) * 196 + p;
        z[idx] = g;
    }
}

// -------------------------------------------------------------------------
// cand = tanh(conv3x3(cat[bu, rh], Wc, bc)); h = (1-z)*h + z*cand
// -------------------------------------------------------------------------
__global__ __launch_bounds__(256) void cand_conv(
    const float* __restrict__ bu, const float* __restrict__ rh,
    const float* __restrict__ z,
    const float* __restrict__ Wc, const float* __restrict__ bc,
    float* __restrict__ h)
{
    int i = blockIdx.x * 256 + threadIdx.x;
    if (i >= 16 * 32 * 196) return;
    int p = i % 196;
    int rest = i / 196;
    int o = rest & 31;
    int b = rest >> 5;
    int y = p / 14, x = p - y * 14;
    int ky0 = (y == 0) ? 1 : 0, ky1 = (y == 13) ? 2 : 3;
    int kx0 = (x == 0) ? 1 : 0, kx1 = (x == 13) ? 2 : 3;

    float acc = bc[o];
    const float* wb  = Wc + o * 432;
    const float* bub = bu + b * 3136;
    const float* rhb = rh + b * 6272;

    for (int ci = 0; ci < 48; ++ci) {
        const float* src = (ci < 16) ? (bub + ci * 196) : (rhb + (ci - 16) * 196);
        const float* w   = wb + ci * 9;
        for (int ky = ky0; ky < ky1; ++ky) {
            int q = p + (ky - 1) * 14 - 1;
            for (int kx = kx0; kx < kx1; ++kx)
                acc += src[q + kx] * w[ky * 3 + kx];
        }
    }
    float cand = tanhf(acc);
    int idx = (b * 32 + o) * 196 + p;
    float zv = z[idx];
    h[idx] = (1.f - zv) * h[idx] + zv * cand;
}

// -------------------------------------------------------------------------
extern "C" void kernel_launch(void* const* d_in, const int* in_sizes, int n_in,
                              void* d_out, int out_size, void* d_ws, size_t ws_size,
                              hipStream_t stream)
{
    (void)in_sizes; (void)n_in; (void)out_size; (void)ws_size;

    const float* x     = (const float*)d_in[0];
    const float* Wg    = (const float*)d_in[1];
    const float* bg    = (const float*)d_in[2];
    const float* Wc    = (const float*)d_in[3];
    const float* bc    = (const float*)d_in[4];
    const float* bu_w[3] = {(const float*)d_in[5], (const float*)d_in[7], (const float*)d_in[9]};
    const float* bu_b[3] = {(const float*)d_in[6], (const float*)d_in[8], (const float*)d_in[10]};
    const float* td_w[2] = {(const float*)d_in[11], (const float*)d_in[13]};
    const float* td_b[2] = {(const float*)d_in[12], (const float*)d_in[14]};
    const float* fc1_w = (const float*)d_in[15];
    const float* fc1_b = (const float*)d_in[16];
    const float* fc2_w = (const float*)d_in[17];
    const float* fc2_b = (const float*)d_in[18];
    float* out = (float*)d_out;

    float* ws     = (float*)d_ws;
    float* hid0   = ws;                  // 100352 each
    float* hid1   = hid0 + 100352;
    float* hid2   = hid1 + 100352;
    float* bu_buf = hid2 + 100352;       // 16*3136
    float* td_buf = bu_buf + 50176;      // 16*9408
    float* rh_buf = td_buf + 150528;     // 16*32*196
    float* z_buf  = rh_buf + 100352;     // 16*32*196
    float* p1_buf = z_buf + 100352;      // 16*100
    float* part   = p1_buf + 1600;       // up to 9408*16*8 = 1204224

    hipMemsetAsync(ws, 0, 3 * 100352 * sizeof(float), stream);

    // td matmul: N=9408, K=6272, S=8, KSLICE=784, grid 294x8=2352
    auto TD = [&](const float* h_src, const float* Wp, const float* bp) {
        matmul_split<1><<<dim3(294, 8), 256, 0, stream>>>(h_src, 0, Wp, part, 9408, 6272, 784, 8);
        reduce_partial<<<588, 256, 0, stream>>>(part, bp, td_buf, 9408, 8);
    };
    // bu matmul (maxpool of h): N=3136, K=6272, S=16, KSLICE=392, grid 98x16
    auto BU = [&](const float* h_src, const float* Wp, const float* bp) {
        matmul_split<1><<<dim3(98, 16), 256, 0, stream>>>(h_src, 0, Wp, part, 3136, 6272, 392, 16);
        reduce_partial<<<196, 256, 0, stream>>>(part, bp, bu_buf, 3136, 16);
    };
    // bu0 matmul (raw x slice): N=3136, K=588, S=8, KSLICE=80, grid 98x8
    auto BU0 = [&](int t) {
        matmul_split<0><<<dim3(98, 8), 256, 0, stream>>>(x + t * 588, 4704, bu_w[0], part, 3136, 588, 80, 8);
        reduce_partial<<<196, 256, 0, stream>>>(part, bu_b[0], bu_buf, 3136, 8);
    };

    for (int t = 0; t < 10; ++t) {       // T + N - 1 = 10
        // ---- node 0 ----
        if (t < 8) {
            BU0(t);
            if (t >= 2) {                // td from hid1 (pre-update: node0 first)
                TD(hid1, td_w[0], td_b[0]);
                gate_conv<true><<<784, 256, 0, stream>>>(bu_buf, hid0, td_buf, Wg, bg, rh_buf, z_buf);
            } else {
                gate_conv<false><<<784, 256, 0, stream>>>(bu_buf, hid0, nullptr, Wg, bg, rh_buf, z_buf);
            }
            cand_conv<<<392, 256, 0, stream>>>(bu_buf, rh_buf, z_buf, Wc, bc, hid0);
        }
        // ---- node 1 (hid0 post-update, hid2 pre-update) ----
        if (t >= 1) {
            BU(hid0, bu_w[1], bu_b[1]);
            const float* wg1 = Wg + 27648;
            const float* bg1 = bg + 64;
            if (t >= 2) {
                TD(hid2, td_w[1], td_b[1]);
                gate_conv<true><<<784, 256, 0, stream>>>(bu_buf, hid1, td_buf, wg1, bg1, rh_buf, z_buf);
            } else {
                gate_conv<false><<<784, 256, 0, stream>>>(bu_buf, hid1, nullptr, wg1, bg1, rh_buf, z_buf);
            }
            cand_conv<<<392, 256, 0, stream>>>(bu_buf, rh_buf, z_buf, Wc + 13824, bc + 32, hid1);
        }
        // ---- node 2 (hid1 post-update; no td) ----
        if (t >= 1) {
            BU(hid1, bu_w[2], bu_b[2]);
            gate_conv<false><<<784, 256, 0, stream>>>(bu_buf, hid2, nullptr,
                                                      Wg + 2 * 27648, bg + 128, rh_buf, z_buf);
            cand_conv<<<392, 256, 0, stream>>>(bu_buf, rh_buf, z_buf, Wc + 2 * 13824, bc + 64, hid2);
        }
    }

    // ---- head ----
    matmul_tn<true, true><<<dim3(7), dim3(256), 0, stream>>>(hid2, 6272, fc1_w, fc1_b, p1_buf, 100, 6272);
    matmul_tn<false, false><<<dim3(1), dim3(256), 0, stream>>>(p1_buf, 100, fc2_w, fc2_b, out, 10, 100);
}

// Round 3
// 8992.032 us; speedup vs baseline: 1.2960x; 1.2960x over previous
//
#include <hip/hip_runtime.h>
#include <math.h>

// B=16, T=8, C=3, H=W=14, HID=32, IND=16, N=3
// hidden[n]: (16,32,14,14) = 100352 floats

// -------------------------------------------------------------------------
// GEMV-style skinny matmul, barrier-free, LDS-free.
// out[b,n] = dot(act[b,:K], W[n,:K])  computed as split-K partials.
// Wave = 16 rows of W x one K-slice. Lane owns 8 fixed columns (off=lane*8);
// act[16][8] cached in registers, amortized over the 16 rows.
// Weight rows streamed as coalesced float4 pairs with next-row prefetch.
// partial[(n*16+b)*S + s] = per-slice dot. KSLICE % 8 == 0, K % 4 == 0.
// -------------------------------------------------------------------------
__global__ __launch_bounds__(256) void gemv16(
    const float* __restrict__ act, int act_stride,
    const float* __restrict__ W,
    float* __restrict__ partial, int N, int K, int KSLICE, int S)
{
    const int wave = threadIdx.x >> 6;
    const int lane = threadIdx.x & 63;
    const int n0   = (blockIdx.x << 6) + (wave << 4);   // 64 rows/block
    const int s    = blockIdx.y;
    const int kb   = s * KSLICE;
    const int len  = min(KSLICE, K - kb);
    const int off  = lane << 3;
    const bool g0  = (off + 4) <= len;
    const bool g1  = (off + 8) <= len;
    const float4 z4 = make_float4(0.f, 0.f, 0.f, 0.f);

    float4 a0[16], a1[16];
#pragma unroll
    for (int b = 0; b < 16; ++b) {
        const float* ap = act + b * act_stride + kb + off;
        a0[b] = g0 ? *(const float4*)(ap)     : z4;
        a1[b] = g1 ? *(const float4*)(ap + 4) : z4;
    }

    const float* wp = W + (size_t)n0 * K + kb + off;
    float4 w0 = g0 ? *(const float4*)(wp)     : z4;
    float4 w1 = g1 ? *(const float4*)(wp + 4) : z4;

    for (int r = 0; r < 16; ++r) {
        float4 nw0 = z4, nw1 = z4;
        if (r < 15) {
            const float* np = wp + (size_t)(r + 1) * K;
            nw0 = g0 ? *(const float4*)(np)     : z4;
            nw1 = g1 ? *(const float4*)(np + 4) : z4;
        }
        float t[16];
#pragma unroll
        for (int b = 0; b < 16; ++b) {
            float v;
            v = w0.x * a0[b].x;
            v = fmaf(w0.y, a0[b].y, v);
            v = fmaf(w0.z, a0[b].z, v);
            v = fmaf(w0.w, a0[b].w, v);
            v = fmaf(w1.x, a1[b].x, v);
            v = fmaf(w1.y, a1[b].y, v);
            v = fmaf(w1.z, a1[b].z, v);
            v = fmaf(w1.w, a1[b].w, v);
            t[b] = v;
        }
#pragma unroll
        for (int m = 1; m < 64; m <<= 1) {
#pragma unroll
            for (int b = 0; b < 16; ++b) t[b] += __shfl_xor(t[b], m, 64);
        }
        if (lane == 0) {
            float* pp = partial + ((size_t)(n0 + r) * 16) * S + s;
#pragma unroll
            for (int b = 0; b < 16; ++b) pp[(size_t)b * S] = t[b];
        }
        w0 = nw0; w1 = nw1;
    }
}

// partial[(n*16+b)*S + s] -> out[b*N + n] = bias[n] + sum_s
__global__ __launch_bounds__(256) void reduce_partial(
    const float* __restrict__ partial, const float* __restrict__ bias,
    float* __restrict__ out, int N, int S)
{
    const int i = blockIdx.x * 256 + threadIdx.x;
    if (i >= N * 16) return;
    const int n = i >> 4, bb = i & 15;
    const float* p = partial + (size_t)i * S;
    float v = bias[n];
    for (int s = 0; s < S; ++s) v += p[s];
    out[bb * N + n] = v;
}

// x[:,t] (16,588 w/ b-stride 4704) -> dst (16,592) zero-padded
__global__ __launch_bounds__(256) void copy_x_pad(
    const float* __restrict__ x, float* __restrict__ dst, int t)
{
    int i = blockIdx.x * 256 + threadIdx.x;
    if (i >= 16 * 592) return;
    int b = i / 592, k = i - b * 592;
    dst[i] = (k < 588) ? x[b * 4704 + t * 588 + k] : 0.f;
}

// MaxPool 3x3 s1 p1 on (16,32,14,14) -> flat (16,6272)
__global__ __launch_bounds__(256) void maxpool3_k(const float* __restrict__ h,
                                                  float* __restrict__ out)
{
    int i = blockIdx.x * 256 + threadIdx.x;
    if (i >= 16 * 32 * 196) return;
    int p = i % 196;
    int y = p / 14, x = p - y * 14;
    const float* base = h + (i - p);
    int y0 = max(y - 1, 0), y1 = min(y + 1, 13);
    int x0 = max(x - 1, 0), x1 = min(x + 1, 13);
    float m = -INFINITY;
    for (int yy = y0; yy <= y1; ++yy)
        for (int xc = x0; xc <= x1; ++xc)
            m = fmaxf(m, base[yy * 14 + xc]);
    out[i] = m;
}

// Gate conv: sigmoid(conv3x3(cat[bu(16ch), h(32ch)] (+ td), Wg, bg))
template<bool HAS_TD>
__global__ __launch_bounds__(256) void gate_conv(
    const float* __restrict__ bu, const float* __restrict__ h,
    const float* __restrict__ td,
    const float* __restrict__ Wg, const float* __restrict__ bg,
    float* __restrict__ rh, float* __restrict__ z)
{
    int i = blockIdx.x * 256 + threadIdx.x;
    if (i >= 16 * 64 * 196) return;
    int p = i % 196;
    int rest = i / 196;
    int o = rest & 63;
    int b = rest >> 6;
    int y = p / 14, x = p - y * 14;
    int ky0 = (y == 0) ? 1 : 0, ky1 = (y == 13) ? 2 : 3;
    int kx0 = (x == 0) ? 1 : 0, kx1 = (x == 13) ? 2 : 3;

    float acc = bg[o];
    const float* wb  = Wg + o * 432;
    const float* bub = bu + b * 3136;
    const float* hb  = h  + b * 6272;
    const float* tdb = HAS_TD ? td + b * 9408 : nullptr;

    for (int ci = 0; ci < 48; ++ci) {
        const float* src = (ci < 16) ? (bub + ci * 196) : (hb + (ci - 16) * 196);
        const float* w   = wb + ci * 9;
        const float* tp  = HAS_TD ? (tdb + ci * 196) : nullptr;
        for (int ky = ky0; ky < ky1; ++ky) {
            int q = p + (ky - 1) * 14 - 1;
            for (int kx = kx0; kx < kx1; ++kx) {
                float v = src[q + kx];
                if (HAS_TD) v += tp[q + kx];
                acc += v * w[ky * 3 + kx];
            }
        }
    }
    float g = 1.f / (1.f + expf(-acc));
    if (o < 32) {
        int idx = (b * 32 + o) * 196 + p;
        rh[idx] = g * h[idx];
    } else {
        int idx = (b * 32 + (o - 32)) * 196 + p;
        z[idx] = g;
    }
}

// cand = tanh(conv3x3(cat[bu, rh], Wc, bc)); h = (1-z)*h + z*cand
__global__ __launch_bounds__(256) void cand_conv(
    const float* __restrict__ bu, const float* __restrict__ rh,
    const float* __restrict__ z,
    const float* __restrict__ Wc, const float* __restrict__ bc,
    float* __restrict__ h)
{
    int i = blockIdx.x * 256 + threadIdx.x;
    if (i >= 16 * 32 * 196) return;
    int p = i % 196;
    int rest = i / 196;
    int o = rest & 31;
    int b = rest >> 5;
    int y = p / 14, x = p - y * 14;
    int ky0 = (y == 0) ? 1 : 0, ky1 = (y == 13) ? 2 : 3;
    int kx0 = (x == 0) ? 1 : 0, kx1 = (x == 13) ? 2 : 3;

    float acc = bc[o];
    const float* wb  = Wc + o * 432;
    const float* bub = bu + b * 3136;
    const float* rhb = rh + b * 6272;

    for (int ci = 0; ci < 48; ++ci) {
        const float* src = (ci < 16) ? (bub + ci * 196) : (rhb + (ci - 16) * 196);
        const float* w   = wb + ci * 9;
        for (int ky = ky0; ky < ky1; ++ky) {
            int q = p + (ky - 1) * 14 - 1;
            for (int kx = kx0; kx < kx1; ++kx)
                acc += src[q + kx] * w[ky * 3 + kx];
        }
    }
    float cand = tanhf(acc);
    int idx = (b * 32 + o) * 196 + p;
    float zv = z[idx];
    h[idx] = (1.f - zv) * h[idx] + zv * cand;
}

// Head matmul (small M): out[b,n] = relu?(dot(relu?(in[b]), W[n]) + bias[n])
template<bool RELU_IN, bool RELU_OUT>
__global__ __launch_bounds__(256) void matmul_tn(
    const float* __restrict__ in, int in_stride,
    const float* __restrict__ W, const float* __restrict__ bias,
    float* __restrict__ out, int N, int K)
{
    __shared__ float lds[16 * 512];
    const int tid  = threadIdx.x;
    const int wave = tid >> 6;
    const int lane = tid & 63;
    const int n0   = blockIdx.x * 16 + wave * 4;

    bool rv[4];
    const float* wr[4];
#pragma unroll
    for (int r = 0; r < 4; ++r) {
        rv[r] = (n0 + r) < N;
        wr[r] = W + (size_t)(n0 + r) * K;
    }

    float acc[4][16];
#pragma unroll
    for (int r = 0; r < 4; ++r)
#pragma unroll
        for (int b = 0; b < 16; ++b) acc[r][b] = 0.f;

    for (int k0 = 0; k0 < K; k0 += 512) {
        const int len = min(512, K - k0);
        __syncthreads();
        for (int i = tid; i < 16 * 512; i += 256) {
            const int b = i >> 9, kk = i & 511;
            if (kk < len) {
                float v = in[b * in_stride + k0 + kk];
                if (RELU_IN) v = fmaxf(v, 0.f);
                lds[i] = v;
            }
        }
        __syncthreads();
        for (int kk = lane * 4; kk < len; kk += 256) {
            float4 w[4];
#pragma unroll
            for (int r = 0; r < 4; ++r)
                w[r] = rv[r] ? *(const float4*)(wr[r] + k0 + kk)
                             : make_float4(0.f, 0.f, 0.f, 0.f);
#pragma unroll
            for (int b = 0; b < 16; ++b) {
                const float4 v = *(const float4*)(&lds[(b << 9) + kk]);
#pragma unroll
                for (int r = 0; r < 4; ++r) {
                    acc[r][b] += w[r].x * v.x + w[r].y * v.y +
                                 w[r].z * v.z + w[r].w * v.w;
                }
            }
        }
    }

#pragma unroll
    for (int r = 0; r < 4; ++r) {
        const float brv = rv[r] ? bias[n0 + r] : 0.f;
#pragma unroll
        for (int b = 0; b < 16; ++b) {
            float v = acc[r][b];
#pragma unroll
            for (int o = 32; o > 0; o >>= 1)
                v += __shfl_down(v, o, 64);
            if (lane == 0 && rv[r]) {
                v += brv;
                if (RELU_OUT) v = fmaxf(v, 0.f);
                out[b * N + (n0 + r)] = v;
            }
        }
    }
}

// -------------------------------------------------------------------------
extern "C" void kernel_launch(void* const* d_in, const int* in_sizes, int n_in,
                              void* d_out, int out_size, void* d_ws, size_t ws_size,
                              hipStream_t stream)
{
    (void)in_sizes; (void)n_in; (void)out_size; (void)ws_size;

    const float* x     = (const float*)d_in[0];
    const float* Wg    = (const float*)d_in[1];
    const float* bg    = (const float*)d_in[2];
    const float* Wc    = (const float*)d_in[3];
    const float* bc    = (const float*)d_in[4];
    const float* bu_w[3] = {(const float*)d_in[5], (const float*)d_in[7], (const float*)d_in[9]};
    const float* bu_b[3] = {(const float*)d_in[6], (const float*)d_in[8], (const float*)d_in[10]};
    const float* td_w[2] = {(const float*)d_in[11], (const float*)d_in[13]};
    const float* td_b[2] = {(const float*)d_in[12], (const float*)d_in[14]};
    const float* fc1_w = (const float*)d_in[15];
    const float* fc1_b = (const float*)d_in[16];
    const float* fc2_w = (const float*)d_in[17];
    const float* fc2_b = (const float*)d_in[18];
    float* out = (float*)d_out;

    float* ws     = (float*)d_ws;
    float* hid0   = ws;                  // 100352 each
    float* hid1   = hid0 + 100352;
    float* hid2   = hid1 + 100352;
    float* bu_buf = hid2 + 100352;       // 16*3136
    float* td_buf = bu_buf + 50176;      // 16*9408
    float* rh_buf = td_buf + 150528;     // 16*32*196
    float* z_buf  = rh_buf + 100352;
    float* p1_buf = z_buf + 100352;      // 1600
    float* xpad   = p1_buf + 1600;       // 16*592
    float* mpA    = xpad + 9472;         // mp(hid0)
    float* mpB    = mpA + 100352;        // mp(hid1)
    float* mpC    = mpB + 100352;        // mp(hid2)
    float* part   = mpC + 100352;        // up to 9408*16*13 = 1956864

    hipMemsetAsync(ws, 0, 3 * 100352 * sizeof(float), stream);

    // td: N=9408, K=6272, KSLICE=512, S=13
    auto TD = [&](const float* mp, const float* Wp, const float* bp) {
        gemv16<<<dim3(147, 13), 256, 0, stream>>>(mp, 6272, Wp, part, 9408, 6272, 512, 13);
        reduce_partial<<<588, 256, 0, stream>>>(part, bp, td_buf, 9408, 13);
    };
    // bu: N=3136, K=6272, KSLICE=512, S=13
    auto BU = [&](const float* mp, const float* Wp, const float* bp) {
        gemv16<<<dim3(49, 13), 256, 0, stream>>>(mp, 6272, Wp, part, 3136, 6272, 512, 13);
        reduce_partial<<<196, 256, 0, stream>>>(part, bp, bu_buf, 3136, 13);
    };

    for (int t = 0; t < 10; ++t) {       // T + N - 1 = 10
        // ---- node 0 ----
        if (t < 8) {
            copy_x_pad<<<37, 256, 0, stream>>>(x, xpad, t);
            // bu0: N=3136, K=588, KSLICE=80, S=8 (act from zero-padded xpad)
            gemv16<<<dim3(49, 8), 256, 0, stream>>>(xpad, 592, bu_w[0], part, 3136, 588, 80, 8);
            reduce_partial<<<196, 256, 0, stream>>>(part, bu_b[0], bu_buf, 3136, 8);
            if (t >= 2) {
                // td from hid1 pre-update this t == mp(hid1) computed at t-1 node2 (mpB)
                TD(mpB, td_w[0], td_b[0]);
                gate_conv<true><<<784, 256, 0, stream>>>(bu_buf, hid0, td_buf, Wg, bg, rh_buf, z_buf);
            } else {
                gate_conv<false><<<784, 256, 0, stream>>>(bu_buf, hid0, nullptr, Wg, bg, rh_buf, z_buf);
            }
            cand_conv<<<392, 256, 0, stream>>>(bu_buf, rh_buf, z_buf, Wc, bc, hid0);
        }
        // ---- node 1 (hid0 post-update, hid2 pre-update) ----
        if (t >= 1) {
            if (t < 8) maxpool3_k<<<392, 256, 0, stream>>>(hid0, mpA);
            // (t>=8: hid0 unchanged since t=7 -> mpA still valid)
            BU(mpA, bu_w[1], bu_b[1]);
            const float* wg1 = Wg + 27648;
            const float* bg1 = bg + 64;
            if (t >= 2) {
                maxpool3_k<<<392, 256, 0, stream>>>(hid2, mpC);
                TD(mpC, td_w[1], td_b[1]);
                gate_conv<true><<<784, 256, 0, stream>>>(bu_buf, hid1, td_buf, wg1, bg1, rh_buf, z_buf);
            } else {
                gate_conv<false><<<784, 256, 0, stream>>>(bu_buf, hid1, nullptr, wg1, bg1, rh_buf, z_buf);
            }
            cand_conv<<<392, 256, 0, stream>>>(bu_buf, rh_buf, z_buf, Wc + 13824, bc + 32, hid1);
        }
        // ---- node 2 (hid1 post-update; no td) ----
        if (t >= 1) {
            maxpool3_k<<<392, 256, 0, stream>>>(hid1, mpB);   // also serves node0 td at t+1
            BU(mpB, bu_w[2], bu_b[2]);
            gate_conv<false><<<784, 256, 0, stream>>>(bu_buf, hid2, nullptr,
                                                      Wg + 2 * 27648, bg + 128, rh_buf, z_buf);
            cand_conv<<<392, 256, 0, stream>>>(bu_buf, rh_buf, z_buf, Wc + 2 * 13824, bc + 64, hid2);
        }
    }

    // ---- head ----
    matmul_tn<true, true><<<dim3(7), dim3(256), 0, stream>>>(hid2, 6272, fc1_w, fc1_b, p1_buf, 100, 6272);
    matmul_tn<false, false><<<dim3(1), dim3(256), 0, stream>>>(p1_buf, 100, fc2_w, fc2_b, out, 10, 100);
}